// Round 1
// baseline (175.460 us; speedup 1.0000x reference)
//
#include <hip/hip_runtime.h>
#include <hip/hip_bf16.h>

#define NN 4096      // total nodes
#define NPER 1024    // nodes per graph
#define DD 128       // feature dim
#define BB 4         // graphs
#define KK 512       // kept per graph

// ---------------------------------------------------------------- init
__global__ void k_init(float* __restrict__ deg, float* __restrict__ acc,
                       int* __restrict__ newid, float* __restrict__ out,
                       int out_size) {
    int i = blockIdx.x * blockDim.x + threadIdx.x;
    if (i < NN) {
        deg[i] = 1.0f;     // self-loop contribution to degree
        acc[i] = 0.0f;
        newid[i] = -1;
    }
    if (i == 0) out[out_size - 1] = 0.0f;  // spectral_loss == 0 (see analysis)
}

// ---------------------------------------------------------------- h = x @ W
// one wave (64 lanes) per row; each lane covers 2 of the 128 features
__global__ void k_h(const float* __restrict__ x, const float* __restrict__ W,
                    float* __restrict__ h) {
    int wid = threadIdx.x >> 6;           // 4 waves / block
    int lane = threadIdx.x & 63;
    int row = blockIdx.x * 4 + wid;
    const float* xr = x + row * DD;
    float v = xr[lane] * W[lane] + xr[lane + 64] * W[lane + 64];
    for (int off = 32; off; off >>= 1) v += __shfl_down(v, off);
    if (lane == 0) h[row] = v;
}

// ---------------------------------------------------------------- degree
__global__ void k_deg(const int* __restrict__ ei, float* __restrict__ deg, int E) {
    int e = blockIdx.x * blockDim.x + threadIdx.x;
    if (e < E) atomicAdd(&deg[ei[E + e]], 1.0f);   // targets (col)
}

// ---------------------------------------------------------------- dinv = deg^-1/2
__global__ void k_dinv(float* __restrict__ deg) {
    int i = blockIdx.x * blockDim.x + threadIdx.x;
    if (i < NN) deg[i] = 1.0f / sqrtf(deg[i]);     // deg >= 1 always
}

// ---------------------------------------------------------------- edge scatter
__global__ void k_scatter(const int* __restrict__ ei, const float* __restrict__ dinv,
                          const float* __restrict__ h, float* __restrict__ acc, int E) {
    int e = blockIdx.x * blockDim.x + threadIdx.x;
    if (e < E) {
        int s = ei[e], c = ei[E + e];
        atomicAdd(&acc[c], dinv[s] * dinv[c] * h[s]);
    }
}

// ---------------------------------------------------------------- score = tanh(...)
__global__ void k_score(const float* __restrict__ acc, const float* __restrict__ dinv,
                        const float* __restrict__ h, const float* __restrict__ bptr,
                        float* __restrict__ score) {
    int i = blockIdx.x * blockDim.x + threadIdx.x;
    if (i < NN) {
        // self-loop term dinv[i]^2 * h[i] added here (not in atomic pass)
        score[i] = tanhf(acc[i] + dinv[i] * dinv[i] * h[i] + bptr[0]);
    }
}

// ---------------------------------------------------------------- per-graph top-K
// full 1024-element bitonic sort in LDS; key = (descending-monotone(score) << 32) | idx
// -> ascending sort == descending score with ties broken by lower index (lax.top_k)
__global__ void k_topk(const float* __restrict__ score, int* __restrict__ perm,
                       int* __restrict__ newid, float* __restrict__ out, int off_b) {
    int g = blockIdx.x;
    int tid = threadIdx.x;
    __shared__ unsigned long long keys[NPER];
    float s = score[g * NPER + tid];
    unsigned int bits = __float_as_uint(s);
    // monotone-increasing map for float order:
    unsigned int m = (bits & 0x80000000u) ? ~bits : (bits | 0x80000000u);
    // invert for descending order
    keys[tid] = ((unsigned long long)(~m) << 32) | (unsigned int)tid;
    __syncthreads();
    for (int k2 = 2; k2 <= NPER; k2 <<= 1) {
        for (int j = k2 >> 1; j > 0; j >>= 1) {
            int ixj = tid ^ j;
            if (ixj > tid) {
                unsigned long long a = keys[tid], b2 = keys[ixj];
                bool up = ((tid & k2) == 0);
                if ((a > b2) == up) { keys[tid] = b2; keys[ixj] = a; }
            }
            __syncthreads();
        }
    }
    if (tid < KK) {
        int node = g * NPER + (int)(keys[tid] & 0xffffffffu);
        int rank = g * KK + tid;
        perm[rank] = node;
        newid[node] = rank;
        out[off_b + rank] = (float)g;   // batch_new
    }
}

// ---------------------------------------------------------------- x_new = x[perm]*score[perm]
__global__ void k_xnew(const float* __restrict__ x, const float* __restrict__ score,
                       const int* __restrict__ perm, float* __restrict__ out) {
    int r = blockIdx.x;
    int d = threadIdx.x;
    int node = perm[r];
    out[r * DD + d] = x[node * DD + d] * score[node];
}

// ---------------------------------------------------------------- edge filter + stable compaction
// single block, 1024 threads, ballot-based scan; preserves original edge order
__global__ void k_edges(const int* __restrict__ ei, const int* __restrict__ newid,
                        float* __restrict__ out, int E, int esel, int off_e) {
    __shared__ int wsum[16];
    __shared__ int wbase[16];
    __shared__ int base;
    int tid = threadIdx.x;
    int lane = tid & 63;
    int wid = tid >> 6;
    if (tid == 0) base = 0;
    __syncthreads();
    for (int chunk = 0; chunk < E; chunk += 1024) {
        int e = chunk + tid;
        int f = 0, r = -1, c = -1;
        if (e < E) {
            r = newid[ei[e]];
            c = newid[ei[E + e]];
            f = (r >= 0 && c >= 0) ? 1 : 0;
        }
        unsigned long long mask = __ballot(f);
        int wpos = __popcll(mask & ((1ull << lane) - 1ull));
        if (lane == 0) wsum[wid] = (int)__popcll(mask);
        __syncthreads();
        if (tid == 0) {
            int s2 = base;
            for (int i2 = 0; i2 < 16; ++i2) { wbase[i2] = s2; s2 += wsum[i2]; }
            base = s2;
        }
        __syncthreads();
        if (f) {
            int pos = wbase[wid] + wpos;
            if (pos < esel) {
                out[off_e + pos] = (float)r;          // row
                out[off_e + esel + pos] = (float)c;   // col
            }
        }
        __syncthreads();
    }
}

// ================================================================ launch
extern "C" void kernel_launch(void* const* d_in, const int* in_sizes, int n_in,
                              void* d_out, int out_size, void* d_ws, size_t ws_size,
                              hipStream_t stream) {
    const float* x  = (const float*)d_in[0];
    const int*   ei = (const int*)d_in[1];
    // d_in[2] = batch (derived analytically, unused)
    const float* W  = (const float*)d_in[3];
    const float* bp = (const float*)d_in[4];
    float* out = (float*)d_out;

    int E = in_sizes[1] / 2;                                // 65536
    int esel = (out_size - BB * KK * DD - BB * KK - 1) / 2; // dynamic kept-edge count
    int off_e = BB * KK * DD;                               // 262144
    int off_b = off_e + 2 * esel;

    float* ws    = (float*)d_ws;
    float* h     = ws;             // NN
    float* deg   = ws + NN;        // NN (becomes dinv)
    float* acc   = ws + 2 * NN;    // NN
    float* score = ws + 3 * NN;    // NN
    int*   perm  = (int*)(ws + 4 * NN);  // BB*KK
    int*   newid = perm + BB * KK;       // NN

    k_init<<<(NN + 255) / 256, 256, 0, stream>>>(deg, acc, newid, out, out_size);
    k_h<<<NN / 4, 256, 0, stream>>>(x, W, h);
    k_deg<<<(E + 255) / 256, 256, 0, stream>>>(ei, deg, E);
    k_dinv<<<(NN + 255) / 256, 256, 0, stream>>>(deg);
    k_scatter<<<(E + 255) / 256, 256, 0, stream>>>(ei, deg, h, acc, E);
    k_score<<<(NN + 255) / 256, 256, 0, stream>>>(acc, deg, h, bp, score);
    k_topk<<<BB, NPER, 0, stream>>>(score, perm, newid, out, off_b);
    k_xnew<<<BB * KK, DD, 0, stream>>>(x, score, perm, out);
    k_edges<<<1, 1024, 0, stream>>>(ei, newid, out, E, esel, off_e);
}

// Round 2
// 150.755 us; speedup vs baseline: 1.1639x; 1.1639x over previous
//
#include <hip/hip_runtime.h>
#include <hip/hip_bf16.h>
#include <hip/hip_cooperative_groups.h>

namespace cg = cooperative_groups;

#define NN 4096      // total nodes
#define NPER 1024    // nodes per graph
#define DD 128       // feature dim
#define BB 4         // graphs
#define KK 512       // kept per graph
#define EE 65536     // total directed edges (2 * 8192 * 4)

// One cooperative kernel: 64 blocks x 1024 threads (grid == EE threads).
// Phases separated by grid.sync(); spectral_loss == 0 analytically (4
// disconnected components before AND after pooling -> Fiedler value 0 both).
__global__ void __launch_bounds__(1024)
fused(const float* __restrict__ x, const int* __restrict__ ei,
      const float* __restrict__ W, const float* __restrict__ bp,
      float* __restrict__ out, float* __restrict__ ws,
      int esel, int off_e, int off_b, int out_size) {
    cg::grid_group grid = cg::this_grid();

    float* h     = ws;            // NN
    float* deg   = ws + NN;       // NN (raw neighbor count, self-loop added inline)
    float* acc   = ws + 2 * NN;   // NN
    float* score = ws + 3 * NN;   // NN
    int*   perm  = (int*)(ws + 4 * NN);   // BB*KK
    int*   newid = perm + BB * KK;        // NN
    int*   counts = newid + NN;           // 64 per-block kept-edge counts

    const int tid  = threadIdx.x;
    const int bid  = blockIdx.x;
    const int gtid = bid * 1024 + tid;
    const int lane = tid & 63;
    const int wid  = tid >> 6;

    __shared__ unsigned long long keys[NPER];
    __shared__ int wsum[16], wbase[16];
    __shared__ int bbase;

    // ---------------- P0: init ----------------
    if (gtid < NN) { deg[gtid] = 0.0f; acc[gtid] = 0.0f; newid[gtid] = -1; }
    if (gtid == 0) out[out_size - 1] = 0.0f;   // spectral_loss
    grid.sync();

    // ---------------- P1: h = x@W (per-wave) + degree atomics ----------------
    atomicAdd(&deg[ei[EE + gtid]], 1.0f);      // one edge-target per thread
    {
        int w = bid * 16 + wid;                // 1024 waves, 4 rows each
        float w0 = W[lane], w1 = W[lane + 64];
        #pragma unroll
        for (int r = 0; r < 4; ++r) {
            int row = w * 4 + r;
            const float* xr = x + row * DD;
            float v = xr[lane] * w0 + xr[lane + 64] * w1;
            for (int off = 32; off; off >>= 1) v += __shfl_down(v, off);
            if (lane == 0) h[row] = v;
        }
    }
    grid.sync();

    // ---------------- P2: edge scatter (dinv inline) ----------------
    {
        int s = ei[gtid], c = ei[EE + gtid];
        float rs = rsqrtf(deg[s] + 1.0f);      // +1 = self loop
        float rc = rsqrtf(deg[c] + 1.0f);
        atomicAdd(&acc[c], rs * rc * h[s]);
    }
    grid.sync();

    // ---------------- P3: score = tanh(acc + dinv^2*h + b) ----------------
    if (gtid < NN) {
        float d = deg[gtid] + 1.0f;
        score[gtid] = tanhf(acc[gtid] + h[gtid] / d + bp[0]);
    }
    grid.sync();

    // ---------------- P4: per-graph top-K via full bitonic sort ----------------
    if (bid < BB) {
        int g = bid;
        float s = score[g * NPER + tid];
        unsigned int bits = __float_as_uint(s);
        unsigned int m = (bits & 0x80000000u) ? ~bits : (bits | 0x80000000u);
        keys[tid] = ((unsigned long long)(~m) << 32) | (unsigned int)tid;
        __syncthreads();
        for (int k2 = 2; k2 <= NPER; k2 <<= 1) {
            for (int j = k2 >> 1; j > 0; j >>= 1) {
                int ixj = tid ^ j;
                if (ixj > tid) {
                    unsigned long long a = keys[tid], b2 = keys[ixj];
                    bool up = ((tid & k2) == 0);
                    if ((a > b2) == up) { keys[tid] = b2; keys[ixj] = a; }
                }
                __syncthreads();
            }
        }
        if (tid < KK) {
            int node = g * NPER + (int)(keys[tid] & 0xffffffffu);
            int rank = g * KK + tid;
            perm[rank] = node;
            newid[node] = rank;
            out[off_b + rank] = (float)g;      // batch_new
        }
    }
    grid.sync();

    // ---------------- P5: x_new gather*scale (float4) + edge flags/counts ----
    {
        // 2048 rows * 32 float4 == 65536 == grid size: one float4 per thread
        int r = gtid >> 5, d4 = gtid & 31;
        int node = perm[r];
        float sc = score[node];
        float4 v = ((const float4*)(x + node * DD))[d4];
        v.x *= sc; v.y *= sc; v.z *= sc; v.w *= sc;
        ((float4*)out)[(r << 5) + d4] = v;
    }
    int er = newid[ei[gtid]];
    int ec = newid[ei[EE + gtid]];
    int f = (er >= 0 && ec >= 0) ? 1 : 0;
    int lpos;
    {
        unsigned long long mask = __ballot(f);
        int wpos = __popcll(mask & ((1ull << lane) - 1ull));
        if (lane == 0) wsum[wid] = (int)__popcll(mask);
        __syncthreads();
        if (tid == 0) {
            int s2 = 0;
            for (int i2 = 0; i2 < 16; ++i2) { wbase[i2] = s2; s2 += wsum[i2]; }
            counts[bid] = s2;
        }
        __syncthreads();
        lpos = wbase[wid] + wpos;              // stable position within block
    }
    grid.sync();

    // ---------------- P6: cross-block base + ordered edge write ----------------
    if (tid == 0) {
        int s2 = 0;
        for (int i2 = 0; i2 < bid; ++i2) s2 += counts[i2];
        bbase = s2;
    }
    __syncthreads();
    if (f) {
        int pos = bbase + lpos;
        if (pos < esel) {
            out[off_e + pos]        = (float)er;   // row
            out[off_e + esel + pos] = (float)ec;   // col
        }
    }
}

// ================================================================ launch
extern "C" void kernel_launch(void* const* d_in, const int* in_sizes, int n_in,
                              void* d_out, int out_size, void* d_ws, size_t ws_size,
                              hipStream_t stream) {
    const float* x  = (const float*)d_in[0];
    const int*   ei = (const int*)d_in[1];
    // d_in[2] = batch (derived analytically, unused)
    const float* W  = (const float*)d_in[3];
    const float* bp = (const float*)d_in[4];
    float* out = (float*)d_out;
    float* ws  = (float*)d_ws;

    int esel  = (out_size - BB * KK * DD - BB * KK - 1) / 2;  // kept-edge count
    int off_e = BB * KK * DD;
    int off_b = off_e + 2 * esel;

    void* args[] = {(void*)&x, (void*)&ei, (void*)&W, (void*)&bp,
                    (void*)&out, (void*)&ws, (void*)&esel, (void*)&off_e,
                    (void*)&off_b, (void*)&out_size};
    hipLaunchCooperativeKernel((const void*)fused, dim3(64), dim3(1024),
                               args, 0, stream);
}